// Round 10
// baseline (262.205 us; speedup 1.0000x reference)
//
#include <hip/hip_runtime.h>

#define NN 30000
#define NE 120000
#define NG2 1875  // ceil(NN/16)
#define TPB 256
#define SB 118    // ceil(NN/256) scan blocks

__device__ __forceinline__ float blo(unsigned u) { return __uint_as_float(u << 16); }
__device__ __forceinline__ float bhi(unsigned u) { return __uint_as_float(u & 0xffff0000u); }

__device__ __forceinline__ unsigned short f2b(float f) {
  unsigned u = __float_as_uint(f);
  return (unsigned short)((u + 0x7fff + ((u >> 16) & 1)) >> 16);  // RNE
}

__global__ void k_zero(int* __restrict__ cnt) {
  int n = blockIdx.x * TPB + threadIdx.x;
  if (n < NN) cnt[n] = 0;
}

// one-time: pre-transposed + pre-swizzled weights Wt[(k,o,i)^sw]
// rows k=0..7 from k_w2, k=8 k_b2, k=9 root
__global__ void k_wprep(const float* __restrict__ kw2, const float* __restrict__ kb2,
                        const float* __restrict__ root, float* __restrict__ Wt) {
  int f = blockIdx.x * TPB + threadIdx.x;
  if (f >= 10240) return;
  int k = f >> 10, rem = f & 1023, i = rem >> 5, o = rem & 31;
  float v;
  if (f < 8192) v = kw2[f];
  else if (f < 9216) v = kb2[f - 8192];
  else v = root[f - 9216];
  Wt[(k * 1024 + o * 32 + i) ^ ((o & 7) << 2)] = v;
}

// kc[e*8+k] = relu(ea@k_w1+k_b1); cnt[dst]++
__global__ void k_prep(const float* __restrict__ ea, const float* __restrict__ w1,
                       const float* __restrict__ b1, const int* __restrict__ dst,
                       float* __restrict__ kc, int* __restrict__ cnt) {
  int e = blockIdx.x * TPB + threadIdx.x;
  if (e >= NE) return;
  float a[6];
#pragma unroll
  for (int i = 0; i < 6; i++) a[i] = ea[e * 6 + i];
#pragma unroll
  for (int k = 0; k < 8; k++) {
    float s = b1[k];
#pragma unroll
    for (int i = 0; i < 6; i++) s = fmaf(a[i], w1[i * 8 + k], s);
    kc[e * 8 + k] = fmaxf(s, 0.f);
  }
  atomicAdd(&cnt[dst[e]], 1);
}

// 3-phase parallel scan
__global__ void k_scan1(const int* __restrict__ cnt, int* __restrict__ bsum) {
  __shared__ int S[TPB];
  int t = threadIdx.x, n = blockIdx.x * TPB + t;
  S[t] = (n < NN) ? cnt[n] : 0;
  __syncthreads();
  for (int off = TPB / 2; off; off >>= 1) {
    if (t < off) S[t] += S[t + off];
    __syncthreads();
  }
  if (t == 0) bsum[blockIdx.x] = S[0];
}

__global__ void k_scan2(int* __restrict__ bsum) {
  __shared__ int S[128];
  int t = threadIdx.x;
  S[t] = (t < SB) ? bsum[t] : 0;
  __syncthreads();
  for (int off = 1; off < 128; off <<= 1) {
    int v = S[t] + ((t >= off) ? S[t - off] : 0);
    __syncthreads();
    S[t] = v;
    __syncthreads();
  }
  if (t < SB) bsum[t] = (t > 0) ? S[t - 1] : 0;
}

__global__ void k_scan3(const int* __restrict__ cnt, const int* __restrict__ bsum,
                        int* __restrict__ rowstart, int* __restrict__ wpos,
                        float* __restrict__ icnt) {
  __shared__ int S[TPB];
  int t = threadIdx.x, n = blockIdx.x * TPB + t;
  int c = (n < NN) ? cnt[n] : 0;
  S[t] = c;
  __syncthreads();
  for (int off = 1; off < TPB; off <<= 1) {
    int v = S[t] + ((t >= off) ? S[t - off] : 0);
    __syncthreads();
    S[t] = v;
    __syncthreads();
  }
  if (n < NN) {
    int r = bsum[blockIdx.x] + S[t] - c;  // exclusive prefix
    rowstart[n] = r;
    wpos[n] = r;
    icnt[n] = 1.f / (float)max(c, 1);
  }
}

// scatter edge payloads into dst-sorted slots: srcs[pos], kcs[pos*8..]
__global__ void k_scatter(const int* __restrict__ dst, const int* __restrict__ src,
                          const float* __restrict__ kc, int* __restrict__ wpos,
                          int* __restrict__ srcs, float* __restrict__ kcs) {
  int e = blockIdx.x * TPB + threadIdx.x;
  if (e >= NE) return;
  int pos = atomicAdd(&wpos[dst[e]], 1);
  srcs[pos] = src[e];
  float4 a = *(const float4*)&kc[e * 8];
  float4 b = *(const float4*)&kc[e * 8 + 4];
  *(float4*)&kcs[(size_t)pos * 8] = a;
  *(float4*)&kcs[(size_t)pos * 8 + 4] = b;
}

// Node transform: 16 nodes/block, one node-pair per thread, kp-OUTER loop so each
// weight ds_read_b128 feeds both nodes once. Weights staged linearly from the
// pre-swizzled Wt (no staging conflicts). P stores: uint4 (k0..7) + dword (k8) + f32 root.
template <int FIRST>
__global__ __launch_bounds__(TPB, 3) void k_node(
    const float* __restrict__ x, const float* __restrict__ fc1w,
    const float* __restrict__ fc1b, const float* __restrict__ h,
    const float* __restrict__ Wt, uint4* __restrict__ Pb4,
    unsigned* __restrict__ Pb1, float* __restrict__ Pr) {
  __shared__ float Wl[10 * 1024];
  __shared__ float hL[512];
  const int tid = threadIdx.x;
  const int base = blockIdx.x * 16;
  {
    const float4* Ws = (const float4*)Wt;
    float4* Wd = (float4*)Wl;
    for (int f = tid; f < 2560; f += TPB) Wd[f] = Ws[f];
  }
  for (int e2 = tid; e2 < 512; e2 += TPB) {
    int ln = e2 >> 5, oo = e2 & 31, n = base + ln;
    float hv = 0.f;
    if (n < NN) hv = FIRST ? fmaf(x[n], fc1w[oo], fc1b[oo]) : h[n * 32 + oo];
    hL[e2] = hv;
  }
  __syncthreads();
  const int g = tid >> 5, o = tid & 31, sw = (o & 7) << 2;
  const int ln0 = g, ln1 = g + 8;
  const int n0 = base + ln0, n1 = base + ln1;
  float4 hv0[8], hv1[8];
#pragma unroll
  for (int c = 0; c < 8; c++) {
    hv0[c] = *(const float4*)&hL[ln0 * 32 + c * 4];
    hv1[c] = *(const float4*)&hL[ln1 * 32 + c * 4];
  }
  uint4 q0, q1;
#pragma unroll 1
  for (int kp = 0; kp < 5; kp++) {
    float aA0 = 0.f, aB0 = 0.f, aA1 = 0.f, aB1 = 0.f;
#pragma unroll
    for (int c = 0; c < 8; c++) {
      const int idx = o * 32 + ((c << 2) ^ sw);
      const float4 wA = *(const float4*)&Wl[(2 * kp) * 1024 + idx];
      const float4 wB = *(const float4*)&Wl[(2 * kp + 1) * 1024 + idx];
      aA0 = fmaf(hv0[c].x, wA.x, aA0); aA1 = fmaf(hv1[c].x, wA.x, aA1);
      aB0 = fmaf(hv0[c].x, wB.x, aB0); aB1 = fmaf(hv1[c].x, wB.x, aB1);
      aA0 = fmaf(hv0[c].y, wA.y, aA0); aA1 = fmaf(hv1[c].y, wA.y, aA1);
      aB0 = fmaf(hv0[c].y, wB.y, aB0); aB1 = fmaf(hv1[c].y, wB.y, aB1);
      aA0 = fmaf(hv0[c].z, wA.z, aA0); aA1 = fmaf(hv1[c].z, wA.z, aA1);
      aB0 = fmaf(hv0[c].z, wB.z, aB0); aB1 = fmaf(hv1[c].z, wB.z, aB1);
      aA0 = fmaf(hv0[c].w, wA.w, aA0); aA1 = fmaf(hv1[c].w, wA.w, aA1);
      aB0 = fmaf(hv0[c].w, wB.w, aB0); aB1 = fmaf(hv1[c].w, wB.w, aB1);
    }
    if (kp < 4) {
      const unsigned p0 = f2b(aA0) | ((unsigned)f2b(aB0) << 16);
      const unsigned p1 = f2b(aA1) | ((unsigned)f2b(aB1) << 16);
      if (kp == 0)      { q0.x = p0; q1.x = p1; }
      else if (kp == 1) { q0.y = p0; q1.y = p1; }
      else if (kp == 2) { q0.z = p0; q1.z = p1; }
      else              { q0.w = p0; q1.w = p1; }
    } else {  // k=8 bias row, k=9 root
      if (n0 < NN) {
        Pb4[(size_t)n0 * 32 + o] = q0;
        Pb1[(size_t)n0 * 32 + o] = f2b(aA0);
        Pr[(size_t)n0 * 32 + o] = aB0;
      }
      if (n1 < NN) {
        Pb4[(size_t)n1 * 32 + o] = q1;
        Pb1[(size_t)n1 * 32 + o] = f2b(aA1);
        Pr[(size_t)n1 * 32 + o] = aB1;
      }
    }
  }
}

// CSR aggregate + activation. FINAL=0: writes h. FINAL=1: out = h @ fc2w + fc2b.
// Per edge: ONE uint4 load (512B/wave) + one dword (bias row).
template <int FINAL>
__global__ void k_agg(const int* __restrict__ rowstart, const int* __restrict__ cnt,
                      const float* __restrict__ icnt, const int* __restrict__ srcs,
                      const float* __restrict__ kcs, const uint4* __restrict__ Pb4,
                      const unsigned* __restrict__ Pb1, const float* __restrict__ Pr,
                      const float* __restrict__ cbias, const float* __restrict__ fc2w,
                      const float* __restrict__ fc2b, float* __restrict__ h,
                      float* __restrict__ out) {
  int t = blockIdx.x * TPB + threadIdx.x;
  int n = t >> 5, o = t & 31;
  if (n >= NN) return;
  int rs = rowstart[n], re = rs + cnt[n];
  float acc = 0.f;
  for (int j = rs; j < re; j++) {
    int s = srcs[j];
    float ck = (o < 8) ? kcs[(size_t)j * 8 + o] : 0.f;
    uint4 w = Pb4[(size_t)s * 32 + o];
    unsigned wb = Pb1[(size_t)s * 32 + o];
    acc += blo(wb);  // bias row, coefficient 1
    acc = fmaf(__shfl(ck, 0, 32), blo(w.x), acc);
    acc = fmaf(__shfl(ck, 1, 32), bhi(w.x), acc);
    acc = fmaf(__shfl(ck, 2, 32), blo(w.y), acc);
    acc = fmaf(__shfl(ck, 3, 32), bhi(w.y), acc);
    acc = fmaf(__shfl(ck, 4, 32), blo(w.z), acc);
    acc = fmaf(__shfl(ck, 5, 32), bhi(w.z), acc);
    acc = fmaf(__shfl(ck, 6, 32), blo(w.w), acc);
    acc = fmaf(__shfl(ck, 7, 32), bhi(w.w), acc);
  }
  float hv = fmaxf(fmaf(acc, icnt[n], Pr[(size_t)n * 32 + o] + cbias[o]), 0.f);
  if (FINAL) {
    float s2 = hv * fc2w[o];
#pragma unroll
    for (int d = 16; d; d >>= 1) s2 += __shfl_xor(s2, d, 32);
    if (o == 0) out[n] = s2 + fc2b[0];
  } else {
    h[(size_t)n * 32 + o] = hv;
  }
}

extern "C" void kernel_launch(void* const* d_in, const int* in_sizes, int n_in,
                              void* d_out, int out_size, void* d_ws, size_t ws_size,
                              hipStream_t stream) {
  const float* x     = (const float*)d_in[0];
  const int*   ei    = (const int*)d_in[1];
  const float* ea    = (const float*)d_in[2];
  const float* fc1w  = (const float*)d_in[3];
  const float* fc1b  = (const float*)d_in[4];
  const float* kw1   = (const float*)d_in[5];
  const float* kb1   = (const float*)d_in[6];
  const float* kw2   = (const float*)d_in[7];
  const float* kb2   = (const float*)d_in[8];
  const float* root  = (const float*)d_in[9];
  const float* cbias = (const float*)d_in[10];
  const float* fc2w  = (const float*)d_in[11];
  const float* fc2b  = (const float*)d_in[12];
  float* out = (float*)d_out;
  const int* srcp = ei;
  const int* dstp = ei + NE;

  float* ws = (float*)d_ws;
  float* kc       = ws;                        // NE*8
  float* kcs      = kc + NE * 8;               // NE*8
  int*   srcs     = (int*)(kcs + NE * 8);      // NE
  float* icnt     = (float*)(srcs + NE);       // NN
  float* h        = icnt + NN;                 // NN*32
  float* Pr       = h + NN * 32;               // NN*32
  int*   cnt      = (int*)(Pr + NN * 32);      // NN
  int*   rowstart = cnt + NN;                  // NN
  int*   wpos     = rowstart + NN;             // NN
  int*   bsum     = wpos + NN;                 // 128
  float* Wt       = (float*)(bsum + 128);      // 10240
  uint4* Pb4      = (uint4*)(Wt + 10240);      // NN*32 uint4
  unsigned* Pb1   = (unsigned*)(Pb4 + (size_t)NN * 32);  // NN*32

  k_zero<<<(NN + TPB - 1) / TPB, TPB, 0, stream>>>(cnt);
  k_wprep<<<40, TPB, 0, stream>>>(kw2, kb2, root, Wt);
  k_prep<<<(NE + TPB - 1) / TPB, TPB, 0, stream>>>(ea, kw1, kb1, dstp, kc, cnt);
  k_scan1<<<SB, TPB, 0, stream>>>(cnt, bsum);
  k_scan2<<<1, 128, 0, stream>>>(bsum);
  k_scan3<<<SB, TPB, 0, stream>>>(cnt, bsum, rowstart, wpos, icnt);
  k_scatter<<<(NE + TPB - 1) / TPB, TPB, 0, stream>>>(dstp, srcp, kc, wpos, srcs, kcs);

  const int agg_grid = (NN * 32 + TPB - 1) / TPB;
  k_node<1><<<NG2, TPB, 0, stream>>>(x, fc1w, fc1b, h, Wt, Pb4, Pb1, Pr);
  for (int l = 0; l < 3; l++) {
    k_agg<0><<<agg_grid, TPB, 0, stream>>>(rowstart, cnt, icnt, srcs, kcs, Pb4,
                                           Pb1, Pr, cbias, fc2w, fc2b, h, out);
    k_node<0><<<NG2, TPB, 0, stream>>>(x, fc1w, fc1b, h, Wt, Pb4, Pb1, Pr);
  }
  k_agg<1><<<agg_grid, TPB, 0, stream>>>(rowstart, cnt, icnt, srcs, kcs, Pb4,
                                         Pb1, Pr, cbias, fc2w, fc2b, h, out);
}